// Round 5
// baseline (171.587 us; speedup 1.0000x reference)
//
#include <hip/hip_runtime.h>

// ---------------------------------------------------------------------------
// Compile-time Clebsch-Gordan / real-basis Wigner-3j generation (exact port of
// the Python reference: _cg_coef, _su2_cg, _q, _w3j, normalization, pw).
// ---------------------------------------------------------------------------

struct W3JT { double v[9][9][9]; };

constexpr double dfact(int n) { double r = 1.0; for (int i = 2; i <= n; ++i) r *= (double)i; return r; }

constexpr double csqrt(double x) {
  if (x <= 0.0) return 0.0;
  double g = x > 1.0 ? x : 1.0;
  for (int i = 0; i < 80; ++i) g = 0.5 * (g + x / g);
  return g;
}

constexpr double cg_coef(int j1, int m1, int j2, int m2, int j3, int m3) {
  if (m1 + m2 != m3) return 0.0;
  int vmin = 0;
  if (j2 - j3 - m1 > vmin) vmin = j2 - j3 - m1;
  if (j1 - j3 + m2 > vmin) vmin = j1 - j3 + m2;
  int vmax = j1 + j2 - j3;
  if (j1 - m1 < vmax) vmax = j1 - m1;
  if (j2 + m2 < vmax) vmax = j2 + m2;
  double pref = csqrt((2.0 * j3 + 1.0) * dfact(j3 + j1 - j2) * dfact(j3 - j1 + j2) * dfact(j1 + j2 - j3) / dfact(j1 + j2 + j3 + 1));
  pref *= csqrt(dfact(j3 + m3) * dfact(j3 - m3) * dfact(j1 + m1) * dfact(j1 - m1) * dfact(j2 + m2) * dfact(j2 - m2));
  double s = 0.0;
  for (int v = vmin; v <= vmax; ++v) {
    double t = 1.0 / (dfact(v) * dfact(j1 + j2 - j3 - v) * dfact(j1 - m1 - v) * dfact(j2 + m2 - v) * dfact(j3 - j2 + m1 + v) * dfact(j3 - j1 - m2 + v));
    s += (v & 1) ? -t : t;
  }
  return pref * s;
}

// Nonzero rows of column `col` of the complex->real change-of-basis matrix
// q(l) (each column has <=2 nonzeros), with the (-i)^l phase applied.
struct QCol { int n; int row[2]; double re[2]; double im[2]; };

constexpr QCol qcol(int l, int col) {
  QCol q{};
  const int lm = l & 3;
  const double pr = (lm == 0) ? 1.0 : (lm == 2) ? -1.0 : 0.0;   // Re((-i)^l)
  const double pi = (lm == 1) ? -1.0 : (lm == 3) ? 1.0 : 0.0;   // Im((-i)^l)
  const int mu = col - l;
  const int am = mu < 0 ? -mu : mu;
  const double is2 = 0.70710678118654752440;
  if (mu == 0) {
    q.n = 1; q.row[0] = l;
    q.re[0] = pr; q.im[0] = pi;
  } else {
    const double s = (am & 1) ? -1.0 : 1.0;   // (-1)^|m|
    double a0 = 0.0, b0 = 0.0, a1 = 0.0, b1 = 0.0;
    if (mu > 0) { a0 = is2; b0 = 0.0;  a1 = s * is2; b1 = 0.0; }      // col l+|m|
    else        { a0 = 0.0; b0 = -is2; a1 = 0.0;     b1 = s * is2; }  // col l-|m|
    q.n = 2;
    q.row[0] = l - am; q.row[1] = l + am;
    q.re[0] = a0 * pr - b0 * pi; q.im[0] = a0 * pi + b0 * pr;
    q.re[1] = a1 * pr - b1 * pi; q.im[1] = a1 * pi + b1 * pr;
  }
  return q;
}

constexpr W3JT make_w3j(int l1, int l2, int l3) {
  W3JT R{};
  double C[9][9][9]{};
  for (int m1 = -l1; m1 <= l1; ++m1)
    for (int m2 = -l2; m2 <= l2; ++m2) {
      int m3 = m1 + m2;
      if (m3 >= -l3 && m3 <= l3)
        C[l1 + m1][l2 + m2][l3 + m3] = cg_coef(l1, m1, l2, m2, l3, m3);
    }
  // C_real[j][l][m] = Re( sum q1[i][j] q2[k][l] conj(q3[n][m]) C[i][k][n] )
  double nrm = 0.0;
  for (int j = 0; j < 2 * l1 + 1; ++j) {
    QCol q1 = qcol(l1, j);
    for (int l = 0; l < 2 * l2 + 1; ++l) {
      QCol q2 = qcol(l2, l);
      for (int m = 0; m < 2 * l3 + 1; ++m) {
        QCol q3 = qcol(l3, m);
        double re = 0.0;
        for (int a = 0; a < q1.n; ++a)
          for (int b = 0; b < q2.n; ++b)
            for (int c = 0; c < q3.n; ++c) {
              double cv = C[q1.row[a]][q2.row[b]][q3.row[c]];
              if (cv == 0.0) continue;
              double ar = q1.re[a], ai = q1.im[a];
              double br = q2.re[b], bi = q2.im[b];
              double cr = q3.re[c], ci = -q3.im[c];   // conj
              double abr = ar * br - ai * bi;
              double abi = ar * bi + ai * br;
              double prr = abr * cr - abi * ci;       // Re(triple product)
              re += prr * cv;
            }
        R.v[j][l][m] = re;
        nrm += re * re;
      }
    }
  }
  double n = csqrt(nrm);
  if (n > 0.0)
    for (int j = 0; j < 2 * l1 + 1; ++j)
      for (int l = 0; l < 2 * l2 + 1; ++l)
        for (int m = 0; m < 2 * l3 + 1; ++m)
          R.v[j][l][m] /= n;
  return R;
}

// instruction counts per output-l (verified against the reference enumeration)
// INS1  = instructions(3,3,4): c-counts {4,6,7,6,4}
// INS21 = instructions(3,4,3): c-counts {4,7,8,8}   (INS22 identical)
constexpr int CNT1[5] = {4, 6, 7, 6, 4};
constexpr int CNT2[4] = {4, 7, 8, 8};

#define NZCHK(V) ((V) > 1e-12 || (V) < -1e-12)

// mid[c*c+k] += w1[IDX] * pw * sum_ij W3J[i][j][k] * xm[a*a+i] * ym[b*b+j]
#define TP_MID(IDX, A, B, C) do { \
  constexpr W3JT T = make_w3j(A, B, C); \
  constexpr double PW = csqrt((2.0 * (C) + 1.0) / (double)CNT1[(C)]); \
  const float wi = w1p[IDX]; \
  float u[2 * (A) + 1]; \
  _Pragma("unroll") for (int i = 0; i < 2 * (A) + 1; ++i) u[i] = wi * xm[(A) * (A) + i]; \
  _Pragma("unroll") for (int i = 0; i < 2 * (A) + 1; ++i) { \
    _Pragma("unroll") for (int j = 0; j < 2 * (B) + 1; ++j) { \
      const float p_ = u[i] * ym[(B) * (B) + j]; \
      _Pragma("unroll") for (int k = 0; k < 2 * (C) + 1; ++k) { \
        if (NZCHK(T.v[i][j][k])) \
          mid[(C) * (C) + k] = __builtin_fmaf((float)(T.v[i][j][k] * PW), p_, mid[(C) * (C) + k]); \
      } \
    } \
  } \
} while (0)

// tv[c*c+k] += pw * sum_ij W3J[i][j][k] * (w21[IDX]*xm_i + w22[IDX]*ym_i) * mid_j
#define TP_OUT(IDX, A, B, C) do { \
  constexpr W3JT T = make_w3j(A, B, C); \
  constexpr double PW = csqrt((2.0 * (C) + 1.0) / (double)CNT2[(C)]); \
  const float wa = w21p[IDX]; \
  const float wb = w22p[IDX]; \
  float u[2 * (A) + 1]; \
  _Pragma("unroll") for (int i = 0; i < 2 * (A) + 1; ++i) \
    u[i] = wa * xm[(A) * (A) + i] + wb * ym[(A) * (A) + i]; \
  _Pragma("unroll") for (int i = 0; i < 2 * (A) + 1; ++i) { \
    _Pragma("unroll") for (int j = 0; j < 2 * (B) + 1; ++j) { \
      const float p_ = u[i] * mid[(B) * (B) + j]; \
      _Pragma("unroll") for (int k = 0; k < 2 * (C) + 1; ++k) { \
        if (NZCHK(T.v[i][j][k])) \
          tv[(C) * (C) + k] = __builtin_fmaf((float)(T.v[i][j][k] * PW), p_, tv[(C) * (C) + k]); \
      } \
    } \
  } \
} while (0)

// ---------------------------------------------------------------------------
// v5: block = 256 threads = 64 edges. Phase-lock breaker:
//  phase 1: coalesced loads (4 lanes/edge, 16B/lane), store out=x+y (L2-dirty),
//           quad-butterfly row means, write xm/ym to LDS (rotate swizzle).
//  phase 2: WAVE 0 ONLY: lane q runs the full constant-folded chain for edge q
//           (chain executed once per 64 edges instead of once per 16 -> 4x
//           less VALU), tv -> LDS.
//  phase 3: all threads read back out from L2, add tv[row], final store.
// No s[16] register hoard (VGPR pressure down), no NT stores.
// ---------------------------------------------------------------------------
__global__ __launch_bounds__(256) void cg2_v5(
    const float4* __restrict__ x4, const float4* __restrict__ y4,
    const float* __restrict__ w1p, const float* __restrict__ w21p,
    const float* __restrict__ w22p, float4* __restrict__ o4, int E)
{
  __shared__ float lmx[64 * 32];   // xm/ym per edge-in-block, rotate-swizzled
  __shared__ float ltv[64 * 16];   // tv per edge-in-block, rotate-swizzled

  const int eL = threadIdx.x >> 2;        // edge-in-block 0..63
  const int g  = threadIdx.x & 3;         // quad lane
  const int e  = blockIdx.x * 64 + eL;
  const bool ok = (e < E);
  const int base = e * 64 + g;            // float4 index

  // ---- phase 1: load, out=x+y, row partials ----
  float px[16], py[16];
  if (ok) {
#pragma unroll
    for (int k = 0; k < 16; ++k) {
      const float4 xv = x4[base + 4 * k];
      const float4 yv = y4[base + 4 * k];
      float4 s;
      s.x = xv.x + yv.x; s.y = xv.y + yv.y;
      s.z = xv.z + yv.z; s.w = xv.w + yv.w;
      o4[base + 4 * k] = s;
      px[k] = (xv.x + xv.y) + (xv.z + xv.w);
      py[k] = (yv.x + yv.y) + (yv.z + yv.w);
    }
  } else {
#pragma unroll
    for (int k = 0; k < 16; ++k) { px[k] = 0.f; py[k] = 0.f; }
  }

  // quad butterflies -> full row means (replicated in all 4 lanes)
#pragma unroll
  for (int k = 0; k < 16; ++k) {
    float rx = px[k] + __shfl_xor(px[k], 1);
    rx += __shfl_xor(rx, 2);
    float ry = py[k] + __shfl_xor(py[k], 1);
    ry += __shfl_xor(ry, 2);
    px[k] = rx * (1.0f / 16.0f);
    py[k] = ry * (1.0f / 16.0f);
  }

  // write xm (j=0..15) and ym (slots 16..31): thread g covers j=4g..4g+3
  if (ok) {
#pragma unroll
    for (int u = 0; u < 4; ++u) {
      const int j = 4 * g + u;
      lmx[eL * 32 + ((j + eL) & 31)]      = px[j];
      lmx[eL * 32 + ((16 + j + eL) & 31)] = py[j];
    }
  }
  __syncthreads();

  // ---- phase 2: wave 0 runs the chain, one edge per lane ----
  if (threadIdx.x < 64) {
    const int q = threadIdx.x;
    const bool ok2 = (blockIdx.x * 64 + q < E);
    float xm[16], ym[16];
#pragma unroll
    for (int j = 0; j < 16; ++j) xm[j] = lmx[q * 32 + ((j + q) & 31)];
#pragma unroll
    for (int j = 0; j < 16; ++j) ym[j] = lmx[q * 32 + ((16 + j + q) & 31)];

    float mid[25];
#pragma unroll
    for (int k = 0; k < 25; ++k) mid[k] = 0.f;

    // INS1 = instructions(3,3,4), reference order
    TP_MID( 0, 0, 0, 0);
    TP_MID( 1, 0, 1, 1);
    TP_MID( 2, 0, 2, 2);
    TP_MID( 3, 0, 3, 3);
    TP_MID( 4, 1, 0, 1);
    TP_MID( 5, 1, 1, 0);
    TP_MID( 6, 1, 1, 2);
    TP_MID( 7, 1, 2, 1);
    TP_MID( 8, 1, 2, 3);
    TP_MID( 9, 1, 3, 2);
    TP_MID(10, 1, 3, 4);
    TP_MID(11, 2, 0, 2);
    TP_MID(12, 2, 1, 1);
    TP_MID(13, 2, 1, 3);
    TP_MID(14, 2, 2, 0);
    TP_MID(15, 2, 2, 2);
    TP_MID(16, 2, 2, 4);
    TP_MID(17, 2, 3, 1);
    TP_MID(18, 2, 3, 3);
    TP_MID(19, 3, 0, 3);
    TP_MID(20, 3, 1, 2);
    TP_MID(21, 3, 1, 4);
    TP_MID(22, 3, 2, 1);
    TP_MID(23, 3, 2, 3);
    TP_MID(24, 3, 3, 0);
    TP_MID(25, 3, 3, 2);
    TP_MID(26, 3, 3, 4);

    float tv[16];
#pragma unroll
    for (int k = 0; k < 16; ++k) tv[k] = 0.f;

    // INS21 == INS22 = instructions(3,4,3); fused via u = w21*xm + w22*ym
    TP_OUT( 0, 0, 0, 0);
    TP_OUT( 1, 0, 1, 1);
    TP_OUT( 2, 0, 2, 2);
    TP_OUT( 3, 0, 3, 3);
    TP_OUT( 4, 1, 0, 1);
    TP_OUT( 5, 1, 1, 0);
    TP_OUT( 6, 1, 1, 2);
    TP_OUT( 7, 1, 2, 1);
    TP_OUT( 8, 1, 2, 3);
    TP_OUT( 9, 1, 3, 2);
    TP_OUT(10, 1, 4, 3);
    TP_OUT(11, 2, 0, 2);
    TP_OUT(12, 2, 1, 1);
    TP_OUT(13, 2, 1, 3);
    TP_OUT(14, 2, 2, 0);
    TP_OUT(15, 2, 2, 2);
    TP_OUT(16, 2, 3, 1);
    TP_OUT(17, 2, 3, 3);
    TP_OUT(18, 2, 4, 2);
    TP_OUT(19, 3, 0, 3);
    TP_OUT(20, 3, 1, 2);
    TP_OUT(21, 3, 2, 1);
    TP_OUT(22, 3, 2, 3);
    TP_OUT(23, 3, 3, 0);
    TP_OUT(24, 3, 3, 2);
    TP_OUT(25, 3, 4, 1);
    TP_OUT(26, 3, 4, 3);

    if (ok2) {
#pragma unroll
      for (int k = 0; k < 16; ++k) ltv[q * 16 + ((k + q) & 15)] = tv[k];
    }
  }
  __syncthreads();

  // ---- phase 3: read back out (L2-hot), add tv, final store ----
  if (ok) {
    float tvv[16];
#pragma unroll
    for (int k = 0; k < 16; ++k) tvv[k] = ltv[eL * 16 + ((k + eL) & 15)];
#pragma unroll
    for (int k = 0; k < 16; ++k) {
      float4 s = o4[base + 4 * k];
      s.x += tvv[k]; s.y += tvv[k];
      s.z += tvv[k]; s.w += tvv[k];
      o4[base + 4 * k] = s;
    }
  }
}

extern "C" void kernel_launch(void* const* d_in, const int* in_sizes, int n_in,
                              void* d_out, int out_size, void* d_ws, size_t ws_size,
                              hipStream_t stream) {
  const float4* x4 = (const float4*)d_in[0];
  const float4* y4 = (const float4*)d_in[1];
  const float* w1p = (const float*)d_in[2];
  const float* w21p = (const float*)d_in[3];
  const float* w22p = (const float*)d_in[4];
  float4* o4 = (float4*)d_out;

  const int E = in_sizes[0] / 256;          // (E, 16, 16) fp32
  const int block = 256;                    // 64 edges per block
  const int grid = (E + 63) / 64;

  cg2_v5<<<grid, block, 0, stream>>>(x4, y4, w1p, w21p, w22p, o4, E);
}

// Round 6
// 127.037 us; speedup vs baseline: 1.3507x; 1.3507x over previous
//
#include <hip/hip_runtime.h>

// ---------------------------------------------------------------------------
// Compile-time Clebsch-Gordan / real-basis Wigner-3j generation (exact port of
// the Python reference: _cg_coef, _su2_cg, _q, _w3j, normalization, pw).
// ---------------------------------------------------------------------------

struct W3JT { double v[9][9][9]; };

constexpr double dfact(int n) { double r = 1.0; for (int i = 2; i <= n; ++i) r *= (double)i; return r; }

constexpr double csqrt(double x) {
  if (x <= 0.0) return 0.0;
  double g = x > 1.0 ? x : 1.0;
  for (int i = 0; i < 80; ++i) g = 0.5 * (g + x / g);
  return g;
}

constexpr double cg_coef(int j1, int m1, int j2, int m2, int j3, int m3) {
  if (m1 + m2 != m3) return 0.0;
  int vmin = 0;
  if (j2 - j3 - m1 > vmin) vmin = j2 - j3 - m1;
  if (j1 - j3 + m2 > vmin) vmin = j1 - j3 + m2;
  int vmax = j1 + j2 - j3;
  if (j1 - m1 < vmax) vmax = j1 - m1;
  if (j2 + m2 < vmax) vmax = j2 + m2;
  double pref = csqrt((2.0 * j3 + 1.0) * dfact(j3 + j1 - j2) * dfact(j3 - j1 + j2) * dfact(j1 + j2 - j3) / dfact(j1 + j2 + j3 + 1));
  pref *= csqrt(dfact(j3 + m3) * dfact(j3 - m3) * dfact(j1 + m1) * dfact(j1 - m1) * dfact(j2 + m2) * dfact(j2 - m2));
  double s = 0.0;
  for (int v = vmin; v <= vmax; ++v) {
    double t = 1.0 / (dfact(v) * dfact(j1 + j2 - j3 - v) * dfact(j1 - m1 - v) * dfact(j2 + m2 - v) * dfact(j3 - j2 + m1 + v) * dfact(j3 - j1 - m2 + v));
    s += (v & 1) ? -t : t;
  }
  return pref * s;
}

// Nonzero rows of column `col` of the complex->real change-of-basis matrix
// q(l) (each column has <=2 nonzeros), with the (-i)^l phase applied.
struct QCol { int n; int row[2]; double re[2]; double im[2]; };

constexpr QCol qcol(int l, int col) {
  QCol q{};
  const int lm = l & 3;
  const double pr = (lm == 0) ? 1.0 : (lm == 2) ? -1.0 : 0.0;   // Re((-i)^l)
  const double pi = (lm == 1) ? -1.0 : (lm == 3) ? 1.0 : 0.0;   // Im((-i)^l)
  const int mu = col - l;
  const int am = mu < 0 ? -mu : mu;
  const double is2 = 0.70710678118654752440;
  if (mu == 0) {
    q.n = 1; q.row[0] = l;
    q.re[0] = pr; q.im[0] = pi;
  } else {
    const double s = (am & 1) ? -1.0 : 1.0;   // (-1)^|m|
    double a0 = 0.0, b0 = 0.0, a1 = 0.0, b1 = 0.0;
    if (mu > 0) { a0 = is2; b0 = 0.0;  a1 = s * is2; b1 = 0.0; }      // col l+|m|
    else        { a0 = 0.0; b0 = -is2; a1 = 0.0;     b1 = s * is2; }  // col l-|m|
    q.n = 2;
    q.row[0] = l - am; q.row[1] = l + am;
    q.re[0] = a0 * pr - b0 * pi; q.im[0] = a0 * pi + b0 * pr;
    q.re[1] = a1 * pr - b1 * pi; q.im[1] = a1 * pi + b1 * pr;
  }
  return q;
}

constexpr W3JT make_w3j(int l1, int l2, int l3) {
  W3JT R{};
  double C[9][9][9]{};
  for (int m1 = -l1; m1 <= l1; ++m1)
    for (int m2 = -l2; m2 <= l2; ++m2) {
      int m3 = m1 + m2;
      if (m3 >= -l3 && m3 <= l3)
        C[l1 + m1][l2 + m2][l3 + m3] = cg_coef(l1, m1, l2, m2, l3, m3);
    }
  // C_real[j][l][m] = Re( sum q1[i][j] q2[k][l] conj(q3[n][m]) C[i][k][n] )
  double nrm = 0.0;
  for (int j = 0; j < 2 * l1 + 1; ++j) {
    QCol q1 = qcol(l1, j);
    for (int l = 0; l < 2 * l2 + 1; ++l) {
      QCol q2 = qcol(l2, l);
      for (int m = 0; m < 2 * l3 + 1; ++m) {
        QCol q3 = qcol(l3, m);
        double re = 0.0;
        for (int a = 0; a < q1.n; ++a)
          for (int b = 0; b < q2.n; ++b)
            for (int c = 0; c < q3.n; ++c) {
              double cv = C[q1.row[a]][q2.row[b]][q3.row[c]];
              if (cv == 0.0) continue;
              double ar = q1.re[a], ai = q1.im[a];
              double br = q2.re[b], bi = q2.im[b];
              double cr = q3.re[c], ci = -q3.im[c];   // conj
              double abr = ar * br - ai * bi;
              double abi = ar * bi + ai * br;
              double prr = abr * cr - abi * ci;       // Re(triple product)
              re += prr * cv;
            }
        R.v[j][l][m] = re;
        nrm += re * re;
      }
    }
  }
  double n = csqrt(nrm);
  if (n > 0.0)
    for (int j = 0; j < 2 * l1 + 1; ++j)
      for (int l = 0; l < 2 * l2 + 1; ++l)
        for (int m = 0; m < 2 * l3 + 1; ++m)
          R.v[j][l][m] /= n;
  return R;
}

// instruction counts per output-l (verified against the reference enumeration)
// INS1  = instructions(3,3,4): c-counts {4,6,7,6,4}
// INS21 = instructions(3,4,3): c-counts {4,7,8,8}   (INS22 identical)
constexpr int CNT1[5] = {4, 6, 7, 6, 4};
constexpr int CNT2[4] = {4, 7, 8, 8};

#define NZCHK(V) ((V) > 1e-12 || (V) < -1e-12)

// mid[c*c+k] += w1[IDX] * pw * sum_ij W3J[i][j][k] * xm[a*a+i] * ym[b*b+j]
#define TP_MID(IDX, A, B, C) do { \
  constexpr W3JT T = make_w3j(A, B, C); \
  constexpr double PW = csqrt((2.0 * (C) + 1.0) / (double)CNT1[(C)]); \
  const float wi = w1p[IDX]; \
  float u[2 * (A) + 1]; \
  _Pragma("unroll") for (int i = 0; i < 2 * (A) + 1; ++i) u[i] = wi * xm[(A) * (A) + i]; \
  _Pragma("unroll") for (int i = 0; i < 2 * (A) + 1; ++i) { \
    _Pragma("unroll") for (int j = 0; j < 2 * (B) + 1; ++j) { \
      const float p_ = u[i] * ym[(B) * (B) + j]; \
      _Pragma("unroll") for (int k = 0; k < 2 * (C) + 1; ++k) { \
        if (NZCHK(T.v[i][j][k])) \
          mid[(C) * (C) + k] = __builtin_fmaf((float)(T.v[i][j][k] * PW), p_, mid[(C) * (C) + k]); \
      } \
    } \
  } \
} while (0)

// tv[c*c+k] += pw * sum_ij W3J[i][j][k] * (w21[IDX]*xm_i + w22[IDX]*ym_i) * mid_j
#define TP_OUT(IDX, A, B, C) do { \
  constexpr W3JT T = make_w3j(A, B, C); \
  constexpr double PW = csqrt((2.0 * (C) + 1.0) / (double)CNT2[(C)]); \
  const float wa = w21p[IDX]; \
  const float wb = w22p[IDX]; \
  float u[2 * (A) + 1]; \
  _Pragma("unroll") for (int i = 0; i < 2 * (A) + 1; ++i) \
    u[i] = wa * xm[(A) * (A) + i] + wb * ym[(A) * (A) + i]; \
  _Pragma("unroll") for (int i = 0; i < 2 * (A) + 1; ++i) { \
    _Pragma("unroll") for (int j = 0; j < 2 * (B) + 1; ++j) { \
      const float p_ = u[i] * mid[(B) * (B) + j]; \
      _Pragma("unroll") for (int k = 0; k < 2 * (C) + 1; ++k) { \
        if (NZCHK(T.v[i][j][k])) \
          tv[(C) * (C) + k] = __builtin_fmaf((float)(T.v[i][j][k] * PW), p_, tv[(C) * (C) + k]); \
      } \
    } \
  } \
} while (0)

// ---------------------------------------------------------------------------
// v6: block = 256 threads = 64 edges. Combines the two proven wins:
//   - s = x+y kept in registers, ONE store at the end (R0/R4: hbm ~409 MB)
//   - chain runs in wave 0 only, one edge per lane (v5: VALU 29% -> 12%)
//  phase 1: coalesced loads (4 lanes/edge, 16B/lane), s in regs,
//           quad-butterfly row means -> LDS (rotate swizzle).
//  phase 2: wave 0: lane q runs the constant-folded chain for edge q, tv->LDS.
//  phase 3: out = s + tv[row], single plain store.
// ---------------------------------------------------------------------------
__global__ __launch_bounds__(256) void cg2_v6(
    const float4* __restrict__ x4, const float4* __restrict__ y4,
    const float* __restrict__ w1p, const float* __restrict__ w21p,
    const float* __restrict__ w22p, float4* __restrict__ o4, int E)
{
  __shared__ float lmx[64 * 32];   // xm/ym per edge-in-block, rotate-swizzled
  __shared__ float ltv[64 * 16];   // tv per edge-in-block, rotate-swizzled

  const int eL = threadIdx.x >> 2;        // edge-in-block 0..63
  const int g  = threadIdx.x & 3;         // quad lane
  const int e  = blockIdx.x * 64 + eL;
  const bool ok = (e < E);
  const int base = e * 64 + g;            // float4 index

  // ---- phase 1: loads, s=x+y in regs, row partials ----
  float4 s[16];
  float px[16], py[16];
  if (ok) {
#pragma unroll
    for (int k = 0; k < 16; ++k) {
      const float4 xv = x4[base + 4 * k];
      const float4 yv = y4[base + 4 * k];
      s[k].x = xv.x + yv.x; s[k].y = xv.y + yv.y;
      s[k].z = xv.z + yv.z; s[k].w = xv.w + yv.w;
      px[k] = (xv.x + xv.y) + (xv.z + xv.w);
      py[k] = (yv.x + yv.y) + (yv.z + yv.w);
    }
  } else {
#pragma unroll
    for (int k = 0; k < 16; ++k) { px[k] = 0.f; py[k] = 0.f; }
  }

  // quad butterflies -> full row means (replicated in all 4 lanes)
#pragma unroll
  for (int k = 0; k < 16; ++k) {
    float rx = px[k] + __shfl_xor(px[k], 1);
    rx += __shfl_xor(rx, 2);
    float ry = py[k] + __shfl_xor(py[k], 1);
    ry += __shfl_xor(ry, 2);
    px[k] = rx * (1.0f / 16.0f);
    py[k] = ry * (1.0f / 16.0f);
  }

  // write xm (slots 0..15) and ym (slots 16..31): thread g covers j=4g..4g+3
  if (ok) {
#pragma unroll
    for (int u = 0; u < 4; ++u) {
      const int j = 4 * g + u;
      lmx[eL * 32 + ((j + eL) & 31)]      = px[j];
      lmx[eL * 32 + ((16 + j + eL) & 31)] = py[j];
    }
  }
  __syncthreads();

  // ---- phase 2: wave 0 runs the chain, one edge per lane ----
  if (threadIdx.x < 64) {
    const int q = threadIdx.x;
    const bool ok2 = (blockIdx.x * 64 + q < E);
    float xm[16], ym[16];
#pragma unroll
    for (int j = 0; j < 16; ++j) xm[j] = lmx[q * 32 + ((j + q) & 31)];
#pragma unroll
    for (int j = 0; j < 16; ++j) ym[j] = lmx[q * 32 + ((16 + j + q) & 31)];

    float mid[25];
#pragma unroll
    for (int k = 0; k < 25; ++k) mid[k] = 0.f;

    // INS1 = instructions(3,3,4), reference order
    TP_MID( 0, 0, 0, 0);
    TP_MID( 1, 0, 1, 1);
    TP_MID( 2, 0, 2, 2);
    TP_MID( 3, 0, 3, 3);
    TP_MID( 4, 1, 0, 1);
    TP_MID( 5, 1, 1, 0);
    TP_MID( 6, 1, 1, 2);
    TP_MID( 7, 1, 2, 1);
    TP_MID( 8, 1, 2, 3);
    TP_MID( 9, 1, 3, 2);
    TP_MID(10, 1, 3, 4);
    TP_MID(11, 2, 0, 2);
    TP_MID(12, 2, 1, 1);
    TP_MID(13, 2, 1, 3);
    TP_MID(14, 2, 2, 0);
    TP_MID(15, 2, 2, 2);
    TP_MID(16, 2, 2, 4);
    TP_MID(17, 2, 3, 1);
    TP_MID(18, 2, 3, 3);
    TP_MID(19, 3, 0, 3);
    TP_MID(20, 3, 1, 2);
    TP_MID(21, 3, 1, 4);
    TP_MID(22, 3, 2, 1);
    TP_MID(23, 3, 2, 3);
    TP_MID(24, 3, 3, 0);
    TP_MID(25, 3, 3, 2);
    TP_MID(26, 3, 3, 4);

    float tv[16];
#pragma unroll
    for (int k = 0; k < 16; ++k) tv[k] = 0.f;

    // INS21 == INS22 = instructions(3,4,3); fused via u = w21*xm + w22*ym
    TP_OUT( 0, 0, 0, 0);
    TP_OUT( 1, 0, 1, 1);
    TP_OUT( 2, 0, 2, 2);
    TP_OUT( 3, 0, 3, 3);
    TP_OUT( 4, 1, 0, 1);
    TP_OUT( 5, 1, 1, 0);
    TP_OUT( 6, 1, 1, 2);
    TP_OUT( 7, 1, 2, 1);
    TP_OUT( 8, 1, 2, 3);
    TP_OUT( 9, 1, 3, 2);
    TP_OUT(10, 1, 4, 3);
    TP_OUT(11, 2, 0, 2);
    TP_OUT(12, 2, 1, 1);
    TP_OUT(13, 2, 1, 3);
    TP_OUT(14, 2, 2, 0);
    TP_OUT(15, 2, 2, 2);
    TP_OUT(16, 2, 3, 1);
    TP_OUT(17, 2, 3, 3);
    TP_OUT(18, 2, 4, 2);
    TP_OUT(19, 3, 0, 3);
    TP_OUT(20, 3, 1, 2);
    TP_OUT(21, 3, 2, 1);
    TP_OUT(22, 3, 2, 3);
    TP_OUT(23, 3, 3, 0);
    TP_OUT(24, 3, 3, 2);
    TP_OUT(25, 3, 4, 1);
    TP_OUT(26, 3, 4, 3);

    if (ok2) {
#pragma unroll
      for (int k = 0; k < 16; ++k) ltv[q * 16 + ((k + q) & 15)] = tv[k];
    }
  }
  __syncthreads();

  // ---- phase 3: out = s + tv[row], single store ----
  if (ok) {
#pragma unroll
    for (int k = 0; k < 16; ++k) {
      const float t = ltv[eL * 16 + ((k + eL) & 15)];
      float4 o;
      o.x = s[k].x + t;
      o.y = s[k].y + t;
      o.z = s[k].z + t;
      o.w = s[k].w + t;
      o4[base + 4 * k] = o;
    }
  }
}

extern "C" void kernel_launch(void* const* d_in, const int* in_sizes, int n_in,
                              void* d_out, int out_size, void* d_ws, size_t ws_size,
                              hipStream_t stream) {
  const float4* x4 = (const float4*)d_in[0];
  const float4* y4 = (const float4*)d_in[1];
  const float* w1p = (const float*)d_in[2];
  const float* w21p = (const float*)d_in[3];
  const float* w22p = (const float*)d_in[4];
  float4* o4 = (float4*)d_out;

  const int E = in_sizes[0] / 256;          // (E, 16, 16) fp32
  const int block = 256;                    // 64 edges per block
  const int grid = (E + 63) / 64;

  cg2_v6<<<grid, block, 0, stream>>>(x4, y4, w1p, w21p, w22p, o4, E);
}